// Round 2
// baseline (610.875 us; speedup 1.0000x reference)
//
#include <hip/hip_runtime.h>
#include <hip/hip_bf16.h>

// Problem constants (N=4, P=2048, D=1024, H=4096, E=8, top-k=2)
#define T_TOK 8192
#define D_DIM 1024
#define H_DIM 4096
#define E_EXP 8
#define BM 128
#define BN 128
#define BK 32
#define MAX_TILES 92   // sum_g ceil(cnt_g/BM) <= T/BM + 28 = 92

typedef __attribute__((ext_vector_type(8))) short bf16x8;
typedef __attribute__((ext_vector_type(4))) float f32x4;

// ---- workspace layout (bytes) ----
#define OFF_COUNTS  0u          // 64 * 4
#define OFF_CURSORS 256u        // 64 * 4
#define OFF_OFFSETS 512u        // 64 * 4
#define OFF_NTILES  768u        // 4
#define OFF_TILES   1024u       // 92 * 16
#define OFF_PAIRS   4096u       // 8192 * 4
#define OFF_PERM    36864u      // 8192 * 4
#define OFF_XG      69632u      // (8192+128) * 1024 * 2  (bf16, gathered, padded)
#define OFF_WBF     (OFF_XG + (size_t)(T_TOK + BM) * D_DIM * 2)  // 8*4096*1024*2

__device__ __forceinline__ unsigned short f2bf(float f) {
  __hip_bfloat16 h = __float2bfloat16(f);
  return *reinterpret_cast<unsigned short*>(&h);
}

__device__ __forceinline__ void gld16(void* lds, const void* g) {
  __builtin_amdgcn_global_load_lds(
      (const __attribute__((address_space(1))) unsigned int*)g,
      (__attribute__((address_space(3))) unsigned int*)lds, 16, 0, 0);
}

// ---- K1b: convert W fp32 -> bf16 ----
__global__ __launch_bounds__(256) void conv_w(const float* __restrict__ W,
                                              unsigned short* __restrict__ Wb) {
  size_t i = ((size_t)blockIdx.x * 256 + threadIdx.x) * 8;
  float4 f0 = *(const float4*)(W + i);
  float4 f1 = *(const float4*)(W + i + 4);
  union { unsigned short u[8]; uint4 v; } o;
  o.u[0] = f2bf(f0.x); o.u[1] = f2bf(f0.y); o.u[2] = f2bf(f0.z); o.u[3] = f2bf(f0.w);
  o.u[4] = f2bf(f1.x); o.u[5] = f2bf(f1.y); o.u[6] = f2bf(f1.z); o.u[7] = f2bf(f1.w);
  *(uint4*)(Wb + i) = o.v;
}

// ---- K1: gating. One wave per token, fp64 accumulation, exact top-2 ----
__global__ __launch_bounds__(256) void gate_topk(const float* __restrict__ x,
                                                 const float* __restrict__ gw,
                                                 const float* __restrict__ gb,
                                                 int* __restrict__ pairs,
                                                 int* __restrict__ counts) {
  int t = blockIdx.x * 4 + (threadIdx.x >> 6);
  int lane = threadIdx.x & 63;
  const float* xr = x + (size_t)t * D_DIM;
  double s[E_EXP];
#pragma unroll
  for (int e = 0; e < E_EXP; ++e) s[e] = 0.0;
  for (int d = lane; d < D_DIM; d += 64) {
    float xv = xr[d];
#pragma unroll
    for (int e = 0; e < E_EXP; ++e)
      s[e] += (double)xv * (double)gw[e * D_DIM + d];
  }
#pragma unroll
  for (int e = 0; e < E_EXP; ++e) {
    double v = s[e];
    for (int off = 32; off; off >>= 1) v += __shfl_down(v, off);
    s[e] = v;
  }
  if (lane == 0) {
    double l[E_EXP];
#pragma unroll
    for (int e = 0; e < E_EXP; ++e) l[e] = s[e] + (double)gb[e];
    int i1 = 0;
#pragma unroll
    for (int e = 1; e < E_EXP; ++e) if (l[e] > l[i1]) i1 = e;  // ties -> lowest idx
    int i2 = -1;
#pragma unroll
    for (int e = 0; e < E_EXP; ++e) {
      if (e == i1) continue;
      if (i2 < 0 || l[e] > l[i2]) i2 = e;
    }
    int a = i1 < i2 ? i1 : i2;
    int c = i1 < i2 ? i2 : i1;
    int pr = a * 8 + c;
    pairs[t] = pr;
    atomicAdd(&counts[pr], 1);
  }
}

// ---- K2: scan counts -> offsets, build tile table ----
__global__ void scan_tiles(const int* __restrict__ counts, int* __restrict__ offsets,
                           int* __restrict__ tiles, int* __restrict__ ntiles) {
  if (threadIdx.x == 0 && blockIdx.x == 0) {
    int run = 0, nt = 0;
    for (int p = 0; p < 64; ++p) {
      offsets[p] = run;
      int c = counts[p];
      for (int i = 0; i < c; i += BM) {
        tiles[nt * 4 + 0] = p;
        tiles[nt * 4 + 1] = run + i;
        tiles[nt * 4 + 2] = (c - i) < BM ? (c - i) : BM;
        tiles[nt * 4 + 3] = 0;
        ++nt;
      }
      run += c;
    }
    *ntiles = nt;
  }
}

// ---- K3: scatter tokens into pair-grouped order + gather x rows as bf16 ----
__global__ __launch_bounds__(256) void gather_x(const float* __restrict__ x,
                                                const int* __restrict__ pairs,
                                                const int* __restrict__ offsets,
                                                int* __restrict__ cursors,
                                                int* __restrict__ perm,
                                                unsigned short* __restrict__ xg) {
  __shared__ int sp;
  int t = blockIdx.x;
  if (threadIdx.x == 0) {
    int pr = pairs[t];
    int pos = offsets[pr] + atomicAdd(&cursors[pr], 1);
    perm[pos] = t;
    sp = pos;
  }
  __syncthreads();
  int pos = sp;
  const float* xr = x + (size_t)t * D_DIM;
  unsigned short* xo = xg + (size_t)pos * D_DIM;
  int d = threadIdx.x * 4;
  float4 f = *(const float4*)(xr + d);
  union { unsigned short u[4]; uint2 v; } o;
  o.u[0] = f2bf(f.x); o.u[1] = f2bf(f.y); o.u[2] = f2bf(f.z); o.u[3] = f2bf(f.w);
  *(uint2*)(xo + d) = o.v;
}

// ---- K4: pair-group GEMM.  out[tok,h] = 0.5*(A.(W[e1]+W[e2])^T + b[e1]+b[e2]) ----
// m97 structure: 128x128 tile, BK=32, 4 waves (2x2), 16x16x32 bf16 MFMA,
// two B panels accumulated into one acc.
__global__ __launch_bounds__(256) void moe_gemm(const unsigned short* __restrict__ xg,
                                                const unsigned short* __restrict__ Wbf,
                                                const float* __restrict__ bvec,
                                                const int* __restrict__ perm,
                                                const int* __restrict__ tiles,
                                                const int* __restrict__ ntiles_p,
                                                float* __restrict__ out) {
  int bt = blockIdx.x;
  if (bt >= *ntiles_p) return;
  int4 tt = ((const int4*)tiles)[bt];
  int pair = tt.x, row0 = tt.y, nrows = tt.z;
  int e1 = pair >> 3, e2 = pair & 7;
  int col0 = blockIdx.y * BN;

  __shared__ __align__(16) unsigned short As[BM * BK];
  __shared__ __align__(16) unsigned short Bs1[BN * BK];
  __shared__ __align__(16) unsigned short Bs2[BN * BK];

  int w = threadIdx.x >> 6;
  int lane = threadIdx.x & 63;
  int wm = w >> 1, wn = w & 1;

  // staging geometry: round r covers rows [r*64, r*64+64); per-wave 1KB chunk
  int srow = w * 16 + (lane >> 2);        // row within 64-row half
  int scol = (lane & 3) * 8;              // bf16 col offset
  int ldsoff = w * 1024 + lane * 16;      // bytes within 4KB half

  const unsigned short* Ag0 = xg + (size_t)(row0 + srow) * D_DIM + scol;
  const unsigned short* B1g0 = Wbf + ((size_t)e1 * H_DIM + col0 + srow) * D_DIM + scol;
  const unsigned short* B2g0 = Wbf + ((size_t)e2 * H_DIM + col0 + srow) * D_DIM + scol;

  int fr = lane & 15;
  int koff = (lane >> 4) * 8;

  f32x4 acc[4][4] = {};

  for (int kt = 0; kt < D_DIM / BK; ++kt) {
    int k0 = kt * BK;
#pragma unroll
    for (int r = 0; r < 2; ++r) {
      gld16((char*)As + r * 4096 + ldsoff, Ag0 + (size_t)r * 64 * D_DIM + k0);
      gld16((char*)Bs1 + r * 4096 + ldsoff, B1g0 + (size_t)r * 64 * D_DIM + k0);
      gld16((char*)Bs2 + r * 4096 + ldsoff, B2g0 + (size_t)r * 64 * D_DIM + k0);
    }
    __syncthreads();

    bf16x8 a[4], b1[4], b2[4];
#pragma unroll
    for (int i = 0; i < 4; ++i) {
      a[i]  = *(const bf16x8*)&As [(wm * 64 + i * 16 + fr) * BK + koff];
      b1[i] = *(const bf16x8*)&Bs1[(wn * 64 + i * 16 + fr) * BK + koff];
      b2[i] = *(const bf16x8*)&Bs2[(wn * 64 + i * 16 + fr) * BK + koff];
    }
#pragma unroll
    for (int mi = 0; mi < 4; ++mi)
#pragma unroll
      for (int ni = 0; ni < 4; ++ni) {
        acc[mi][ni] = __builtin_amdgcn_mfma_f32_16x16x32_bf16(a[mi], b1[ni], acc[mi][ni], 0, 0, 0);
        acc[mi][ni] = __builtin_amdgcn_mfma_f32_16x16x32_bf16(a[mi], b2[ni], acc[mi][ni], 0, 0, 0);
      }
    __syncthreads();
  }

  // epilogue: C/D layout col=lane&15, row=(lane>>4)*4+j (verified m89/m91)
  int toks[4][4];
  bool okr[4][4];
#pragma unroll
  for (int mi = 0; mi < 4; ++mi)
#pragma unroll
    for (int j = 0; j < 4; ++j) {
      int rl = wm * 64 + mi * 16 + (lane >> 4) * 4 + j;
      okr[mi][j] = rl < nrows;
      toks[mi][j] = okr[mi][j] ? perm[row0 + rl] : 0;
    }
#pragma unroll
  for (int ni = 0; ni < 4; ++ni) {
    int h = col0 + wn * 64 + ni * 16 + fr;
    float bias = 0.5f * (bvec[e1 * H_DIM + h] + bvec[e2 * H_DIM + h]);
#pragma unroll
    for (int mi = 0; mi < 4; ++mi)
#pragma unroll
      for (int j = 0; j < 4; ++j)
        if (okr[mi][j])
          out[(size_t)toks[mi][j] * H_DIM + h] = 0.5f * acc[mi][ni][j] + bias;
  }
}

extern "C" void kernel_launch(void* const* d_in, const int* in_sizes, int n_in,
                              void* d_out, int out_size, void* d_ws, size_t ws_size,
                              hipStream_t stream) {
  const float* seq = (const float*)d_in[0];   // [4,2048,1024]
  const float* gw  = (const float*)d_in[1];   // [8,1024]
  const float* gb  = (const float*)d_in[2];   // [8]
  const float* W   = (const float*)d_in[3];   // [8,4096,1024]
  const float* bb  = (const float*)d_in[4];   // [8,4096]
  float* out = (float*)d_out;

  char* ws = (char*)d_ws;
  int* counts  = (int*)(ws + OFF_COUNTS);
  int* cursors = (int*)(ws + OFF_CURSORS);
  int* offsets = (int*)(ws + OFF_OFFSETS);
  int* ntiles  = (int*)(ws + OFF_NTILES);
  int* tiles   = (int*)(ws + OFF_TILES);
  int* pairs   = (int*)(ws + OFF_PAIRS);
  int* perm    = (int*)(ws + OFF_PERM);
  unsigned short* xg  = (unsigned short*)(ws + OFF_XG);
  unsigned short* Wbf = (unsigned short*)(ws + OFF_WBF);

  hipMemsetAsync(d_ws, 0, 1024, stream);

  conv_w<<<dim3((E_EXP * H_DIM * D_DIM) / 8 / 256), dim3(256), 0, stream>>>(W, Wbf);
  gate_topk<<<dim3(T_TOK / 4), dim3(256), 0, stream>>>(seq, gw, gb, pairs, counts);
  scan_tiles<<<dim3(1), dim3(64), 0, stream>>>(counts, offsets, tiles, ntiles);
  gather_x<<<dim3(T_TOK), dim3(256), 0, stream>>>(seq, pairs, offsets, cursors, perm, xg);
  moe_gemm<<<dim3(MAX_TILES, H_DIM / BN), dim3(256), 0, stream>>>(xg, Wbf, bb, perm, tiles, ntiles, out);
}

// Round 3
// 575.606 us; speedup vs baseline: 1.0613x; 1.0613x over previous
//
#include <hip/hip_runtime.h>
#include <hip/hip_bf16.h>

// Problem constants (N=4, P=2048, D=1024, H=4096, E=8, top-k=2)
#define T_TOK 8192
#define D_DIM 1024
#define H_DIM 4096
#define E_EXP 8
#define BM 128
#define BN 128
#define BK 64
#define MAX_TILES 92   // sum_g ceil(cnt_g/BM) <= T/BM + 28 = 92

typedef __attribute__((ext_vector_type(8))) short bf16x8;
typedef __attribute__((ext_vector_type(4))) float f32x4;

// ---- workspace layout (bytes) ----
#define OFF_COUNTS  0u          // 64 * 4
#define OFF_CURSORS 256u        // 64 * 4
#define OFF_OFFSETS 512u        // 64 * 4
#define OFF_NTILES  768u        // 4
#define OFF_TILES   1024u       // 92 * 16
#define OFF_PAIRS   4096u       // 8192 * 4
#define OFF_PERM    36864u      // 8192 * 4
#define OFF_XG      69632u      // (8192+128) * 1024 * 2  (bf16, gathered, padded)
#define OFF_WBF     (OFF_XG + (size_t)(T_TOK + BM) * D_DIM * 2)  // 8*4096*1024*2

__device__ __forceinline__ unsigned short f2bf(float f) {
  __hip_bfloat16 h = __float2bfloat16(f);
  return *reinterpret_cast<unsigned short*>(&h);
}

__device__ __forceinline__ void gld16(void* lds, const void* g) {
  __builtin_amdgcn_global_load_lds(
      (const __attribute__((address_space(1))) unsigned int*)g,
      (__attribute__((address_space(3))) unsigned int*)lds, 16, 0, 0);
}

// ---- K1b: convert W fp32 -> bf16 ----
__global__ __launch_bounds__(256) void conv_w(const float* __restrict__ W,
                                              unsigned short* __restrict__ Wb) {
  size_t i = ((size_t)blockIdx.x * 256 + threadIdx.x) * 8;
  float4 f0 = *(const float4*)(W + i);
  float4 f1 = *(const float4*)(W + i + 4);
  union { unsigned short u[8]; uint4 v; } o;
  o.u[0] = f2bf(f0.x); o.u[1] = f2bf(f0.y); o.u[2] = f2bf(f0.z); o.u[3] = f2bf(f0.w);
  o.u[4] = f2bf(f1.x); o.u[5] = f2bf(f1.y); o.u[6] = f2bf(f1.z); o.u[7] = f2bf(f1.w);
  *(uint4*)(Wb + i) = o.v;
}

// ---- K1: gating. One wave per token, fp64 accumulation, exact top-2 ----
__global__ __launch_bounds__(256) void gate_topk(const float* __restrict__ x,
                                                 const float* __restrict__ gw,
                                                 const float* __restrict__ gb,
                                                 int* __restrict__ pairs,
                                                 int* __restrict__ counts) {
  int t = blockIdx.x * 4 + (threadIdx.x >> 6);
  int lane = threadIdx.x & 63;
  const float* xr = x + (size_t)t * D_DIM;
  double s[E_EXP];
#pragma unroll
  for (int e = 0; e < E_EXP; ++e) s[e] = 0.0;
  for (int d = lane; d < D_DIM; d += 64) {
    float xv = xr[d];
#pragma unroll
    for (int e = 0; e < E_EXP; ++e)
      s[e] += (double)xv * (double)gw[e * D_DIM + d];
  }
#pragma unroll
  for (int e = 0; e < E_EXP; ++e) {
    double v = s[e];
    for (int off = 32; off; off >>= 1) v += __shfl_down(v, off);
    s[e] = v;
  }
  if (lane == 0) {
    double l[E_EXP];
#pragma unroll
    for (int e = 0; e < E_EXP; ++e) l[e] = s[e] + (double)gb[e];
    int i1 = 0;
#pragma unroll
    for (int e = 1; e < E_EXP; ++e) if (l[e] > l[i1]) i1 = e;  // ties -> lowest idx
    int i2 = -1;
#pragma unroll
    for (int e = 0; e < E_EXP; ++e) {
      if (e == i1) continue;
      if (i2 < 0 || l[e] > l[i2]) i2 = e;
    }
    int a = i1 < i2 ? i1 : i2;
    int c = i1 < i2 ? i2 : i1;
    int pr = a * 8 + c;
    pairs[t] = pr;
    atomicAdd(&counts[pr], 1);
  }
}

// ---- K2: scan counts -> offsets, build tile table ----
__global__ void scan_tiles(const int* __restrict__ counts, int* __restrict__ offsets,
                           int* __restrict__ tiles, int* __restrict__ ntiles) {
  if (threadIdx.x == 0 && blockIdx.x == 0) {
    int run = 0, nt = 0;
    for (int p = 0; p < 64; ++p) {
      offsets[p] = run;
      int c = counts[p];
      for (int i = 0; i < c; i += BM) {
        tiles[nt * 4 + 0] = p;
        tiles[nt * 4 + 1] = run + i;
        tiles[nt * 4 + 2] = (c - i) < BM ? (c - i) : BM;
        tiles[nt * 4 + 3] = 0;
        ++nt;
      }
      run += c;
    }
    *ntiles = nt;
  }
}

// ---- K3: scatter tokens into pair-grouped order + gather x rows as bf16 ----
__global__ __launch_bounds__(256) void gather_x(const float* __restrict__ x,
                                                const int* __restrict__ pairs,
                                                const int* __restrict__ offsets,
                                                int* __restrict__ cursors,
                                                int* __restrict__ perm,
                                                unsigned short* __restrict__ xg) {
  __shared__ int sp;
  int t = blockIdx.x;
  if (threadIdx.x == 0) {
    int pr = pairs[t];
    int pos = offsets[pr] + atomicAdd(&cursors[pr], 1);
    perm[pos] = t;
    sp = pos;
  }
  __syncthreads();
  int pos = sp;
  const float* xr = x + (size_t)t * D_DIM;
  unsigned short* xo = xg + (size_t)pos * D_DIM;
  int d = threadIdx.x * 4;
  float4 f = *(const float4*)(xr + d);
  union { unsigned short u[4]; uint2 v; } o;
  o.u[0] = f2bf(f.x); o.u[1] = f2bf(f.y); o.u[2] = f2bf(f.z); o.u[3] = f2bf(f.w);
  *(uint2*)(xo + d) = o.v;
}

// ---- K4: pair-group GEMM.  out[tok,h] = 0.5*(A.(W[e1]+W[e2])^T + b[e1]+b[e2]) ----
// 128x128 tile, BK=64, 4 waves (2x2), 16x16x32 bf16 MFMA, two B panels into one acc.
// LDS: 3 linear [128][64] bf16 panels staged via global_load_lds (width 16).
// XOR swizzle (rule #21): LDS dest linear; global SOURCE col pre-swizzled
// (slot ^= row&7); fragment reads apply the same XOR -> conflict-free ds_read_b128.
__global__ __launch_bounds__(256) void moe_gemm(const unsigned short* __restrict__ xg,
                                                const unsigned short* __restrict__ Wbf,
                                                const float* __restrict__ bvec,
                                                const int* __restrict__ perm,
                                                const int* __restrict__ tiles,
                                                const int* __restrict__ ntiles_p,
                                                float* __restrict__ out) {
  int bt = blockIdx.x;
  if (bt >= *ntiles_p) return;
  int4 tt = ((const int4*)tiles)[bt];
  int pair = tt.x, row0 = tt.y, nrows = tt.z;
  int e1 = pair >> 3, e2 = pair & 7;
  int col0 = blockIdx.y * BN;

  __shared__ __align__(16) unsigned short As[BM * BK];
  __shared__ __align__(16) unsigned short Bs1[BN * BK];
  __shared__ __align__(16) unsigned short Bs2[BN * BK];

  int w = threadIdx.x >> 6;
  int lane = threadIdx.x & 63;
  int wm = w >> 1, wn = w & 1;

  // staging geometry: round r (0..3) covers rows [r*32, r*32+32)
  // wave w covers rows r*32 + w*8 + (lane>>3); 16B chunk (lane&7) of the 128B row,
  // source-swizzled: chunk_src = (lane&7) ^ (row&7), row&7 == lane>>3
  int srow = w * 8 + (lane >> 3);                 // row within 32-row round
  int scol = (((lane & 7) ^ (lane >> 3)) * 8);    // element offset, pre-swizzled
  int ldsoff = w * 1024 + lane * 16;              // linear bytes within 4KB round

  const unsigned short* Ag0  = xg + (size_t)(row0 + srow) * D_DIM + scol;
  const unsigned short* B1g0 = Wbf + ((size_t)e1 * H_DIM + col0 + srow) * D_DIM + scol;
  const unsigned short* B2g0 = Wbf + ((size_t)e2 * H_DIM + col0 + srow) * D_DIM + scol;

  int fr = lane & 15;
  int kslot = (lane >> 4) * 16;   // byte offset of this lane's 16B slot in 64B half
  int swz = (fr & 7) << 4;        // read-side XOR key (row&7 == fr&7)

  f32x4 acc[4][4] = {};

  for (int kt = 0; kt < D_DIM / BK; ++kt) {
    int k0 = kt * BK;
#pragma unroll
    for (int r = 0; r < 4; ++r) {
      gld16((char*)As  + r * 4096 + ldsoff, Ag0  + (size_t)r * 32 * D_DIM + k0);
      gld16((char*)Bs1 + r * 4096 + ldsoff, B1g0 + (size_t)r * 32 * D_DIM + k0);
      gld16((char*)Bs2 + r * 4096 + ldsoff, B2g0 + (size_t)r * 32 * D_DIM + k0);
    }
    __syncthreads();

#pragma unroll
    for (int ks = 0; ks < 2; ++ks) {
      int cb = (ks * 64 + kslot) ^ swz;   // swizzled byte col within 128B row
      bf16x8 a[4], b1[4], b2[4];
#pragma unroll
      for (int i = 0; i < 4; ++i) {
        a[i]  = *(const bf16x8*)((const char*)As  + (wm * 64 + i * 16 + fr) * 128 + cb);
        b1[i] = *(const bf16x8*)((const char*)Bs1 + (wn * 64 + i * 16 + fr) * 128 + cb);
        b2[i] = *(const bf16x8*)((const char*)Bs2 + (wn * 64 + i * 16 + fr) * 128 + cb);
      }
#pragma unroll
      for (int mi = 0; mi < 4; ++mi)
#pragma unroll
        for (int ni = 0; ni < 4; ++ni) {
          acc[mi][ni] = __builtin_amdgcn_mfma_f32_16x16x32_bf16(a[mi], b1[ni], acc[mi][ni], 0, 0, 0);
          acc[mi][ni] = __builtin_amdgcn_mfma_f32_16x16x32_bf16(a[mi], b2[ni], acc[mi][ni], 0, 0, 0);
        }
    }
    __syncthreads();
  }

  // epilogue: C/D layout col=lane&15, row=(lane>>4)*4+j (verified m89/m91)
  int toks[4][4];
  bool okr[4][4];
#pragma unroll
  for (int mi = 0; mi < 4; ++mi)
#pragma unroll
    for (int j = 0; j < 4; ++j) {
      int rl = wm * 64 + mi * 16 + (lane >> 4) * 4 + j;
      okr[mi][j] = rl < nrows;
      toks[mi][j] = okr[mi][j] ? perm[row0 + rl] : 0;
    }
#pragma unroll
  for (int ni = 0; ni < 4; ++ni) {
    int h = col0 + wn * 64 + ni * 16 + fr;
    float bias = 0.5f * (bvec[e1 * H_DIM + h] + bvec[e2 * H_DIM + h]);
#pragma unroll
    for (int mi = 0; mi < 4; ++mi)
#pragma unroll
      for (int j = 0; j < 4; ++j)
        if (okr[mi][j])
          out[(size_t)toks[mi][j] * H_DIM + h] = 0.5f * acc[mi][ni][j] + bias;
  }
}

extern "C" void kernel_launch(void* const* d_in, const int* in_sizes, int n_in,
                              void* d_out, int out_size, void* d_ws, size_t ws_size,
                              hipStream_t stream) {
  const float* seq = (const float*)d_in[0];   // [4,2048,1024]
  const float* gw  = (const float*)d_in[1];   // [8,1024]
  const float* gb  = (const float*)d_in[2];   // [8]
  const float* W   = (const float*)d_in[3];   // [8,4096,1024]
  const float* bb  = (const float*)d_in[4];   // [8,4096]
  float* out = (float*)d_out;

  char* ws = (char*)d_ws;
  int* counts  = (int*)(ws + OFF_COUNTS);
  int* cursors = (int*)(ws + OFF_CURSORS);
  int* offsets = (int*)(ws + OFF_OFFSETS);
  int* ntiles  = (int*)(ws + OFF_NTILES);
  int* tiles   = (int*)(ws + OFF_TILES);
  int* pairs   = (int*)(ws + OFF_PAIRS);
  int* perm    = (int*)(ws + OFF_PERM);
  unsigned short* xg  = (unsigned short*)(ws + OFF_XG);
  unsigned short* Wbf = (unsigned short*)(ws + OFF_WBF);

  hipMemsetAsync(d_ws, 0, 1024, stream);

  conv_w<<<dim3((E_EXP * H_DIM * D_DIM) / 8 / 256), dim3(256), 0, stream>>>(W, Wbf);
  gate_topk<<<dim3(T_TOK / 4), dim3(256), 0, stream>>>(seq, gw, gb, pairs, counts);
  scan_tiles<<<dim3(1), dim3(64), 0, stream>>>(counts, offsets, tiles, ntiles);
  gather_x<<<dim3(T_TOK), dim3(256), 0, stream>>>(seq, pairs, offsets, cursors, perm, xg);
  moe_gemm<<<dim3(MAX_TILES, H_DIM / BN), dim3(256), 0, stream>>>(xg, Wbf, bb, perm, tiles, ntiles, out);
}

// Round 4
// 531.897 us; speedup vs baseline: 1.1485x; 1.0822x over previous
//
#include <hip/hip_runtime.h>
#include <hip/hip_bf16.h>

// Problem constants (N=4, P=2048, D=1024, H=4096, E=8, top-k=2)
#define T_TOK 8192
#define D_DIM 1024
#define H_DIM 4096
#define E_EXP 8
#define BM 128
#define BN 128
#define BK 64
#define MAX_TILES 92   // sum_g ceil(cnt_g/BM) <= T/BM + 28 = 92

typedef __attribute__((ext_vector_type(8))) short bf16x8;
typedef __attribute__((ext_vector_type(4))) float f32x4;

// ---- workspace layout (bytes) ----
#define OFF_COUNTS  0u          // 64 * 4
#define OFF_CURSORS 256u        // 64 * 4
#define OFF_OFFSETS 512u        // 64 * 4
#define OFF_NTILES  768u        // 4
#define OFF_TILES   1024u       // 92 * 16
#define OFF_PAIRS   4096u       // 8192 * 4
#define OFF_PERM    36864u      // 8192 * 4
#define OFF_XBF     69632u      // 8192 * 1024 * 2 (bf16, token order)
#define OFF_WBF     (OFF_XBF + (size_t)T_TOK * D_DIM * 2)  // 8*4096*1024*2

__device__ __forceinline__ unsigned short f2bf(float f) {
  __hip_bfloat16 h = __float2bfloat16(f);
  return *reinterpret_cast<unsigned short*>(&h);
}

__device__ __forceinline__ void gld16(void* lds, const void* g) {
  __builtin_amdgcn_global_load_lds(
      (const __attribute__((address_space(1))) unsigned int*)g,
      (__attribute__((address_space(3))) unsigned int*)lds, 16, 0, 0);
}

// ---- K1b: convert W fp32 -> bf16 ----
__global__ __launch_bounds__(256) void conv_w(const float* __restrict__ W,
                                              unsigned short* __restrict__ Wb) {
  size_t i = ((size_t)blockIdx.x * 256 + threadIdx.x) * 8;
  float4 f0 = *(const float4*)(W + i);
  float4 f1 = *(const float4*)(W + i + 4);
  union { unsigned short u[8]; uint4 v; } o;
  o.u[0] = f2bf(f0.x); o.u[1] = f2bf(f0.y); o.u[2] = f2bf(f0.z); o.u[3] = f2bf(f0.w);
  o.u[4] = f2bf(f1.x); o.u[5] = f2bf(f1.y); o.u[6] = f2bf(f1.z); o.u[7] = f2bf(f1.w);
  *(uint4*)(Wb + i) = o.v;
}

// ---- K1: gating + x->bf16. One wave per token, float4 reads, fp64 accum ----
__global__ __launch_bounds__(256) void gate_topk(const float* __restrict__ x,
                                                 const float* __restrict__ gw,
                                                 const float* __restrict__ gb,
                                                 int* __restrict__ pairs,
                                                 int* __restrict__ counts,
                                                 unsigned short* __restrict__ xbf) {
  int t = blockIdx.x * 4 + (threadIdx.x >> 6);
  int lane = threadIdx.x & 63;
  const float* xr = x + (size_t)t * D_DIM;
  unsigned short* xo = xbf + (size_t)t * D_DIM;
  double s[E_EXP];
#pragma unroll
  for (int e = 0; e < E_EXP; ++e) s[e] = 0.0;
#pragma unroll
  for (int it = 0; it < 4; ++it) {
    int idx = it * 256 + lane * 4;
    float4 f = *(const float4*)(xr + idx);
    union { unsigned short u[4]; uint2 v; } o;
    o.u[0] = f2bf(f.x); o.u[1] = f2bf(f.y); o.u[2] = f2bf(f.z); o.u[3] = f2bf(f.w);
    *(uint2*)(xo + idx) = o.v;
#pragma unroll
    for (int e = 0; e < E_EXP; ++e) {
      const float4 g = *(const float4*)(gw + e * D_DIM + idx);
      s[e] = fma((double)f.x, (double)g.x, s[e]);
      s[e] = fma((double)f.y, (double)g.y, s[e]);
      s[e] = fma((double)f.z, (double)g.z, s[e]);
      s[e] = fma((double)f.w, (double)g.w, s[e]);
    }
  }
#pragma unroll
  for (int e = 0; e < E_EXP; ++e) {
    double v = s[e];
    for (int off = 32; off; off >>= 1) v += __shfl_down(v, off);
    s[e] = v;
  }
  if (lane == 0) {
    double l[E_EXP];
#pragma unroll
    for (int e = 0; e < E_EXP; ++e) l[e] = s[e] + (double)gb[e];
    int i1 = 0;
#pragma unroll
    for (int e = 1; e < E_EXP; ++e) if (l[e] > l[i1]) i1 = e;  // ties -> lowest idx
    int i2 = -1;
#pragma unroll
    for (int e = 0; e < E_EXP; ++e) {
      if (e == i1) continue;
      if (i2 < 0 || l[e] > l[i2]) i2 = e;
    }
    int a = i1 < i2 ? i1 : i2;
    int c = i1 < i2 ? i2 : i1;
    int pr = a * 8 + c;
    pairs[t] = pr;
    atomicAdd(&counts[pr], 1);
  }
}

// ---- K2: parallel scan (1 wave): counts -> offsets, tile table ----
__global__ __launch_bounds__(64) void scan_tiles(const int* __restrict__ counts,
                                                 int* __restrict__ offsets,
                                                 int* __restrict__ tiles,
                                                 int* __restrict__ ntiles) {
  int p = threadIdx.x;              // pair id 0..63
  int c = counts[p];
  int nt = (c + BM - 1) >> 7;       // tiles for this pair
  int ic = c, itt = nt;             // inclusive scans
  for (int off = 1; off < 64; off <<= 1) {
    int vc = __shfl_up(ic, off);
    int vt = __shfl_up(itt, off);
    if (p >= off) { ic += vc; itt += vt; }
  }
  int oc = ic - c;                  // exclusive prefix (row offset)
  int ot = itt - nt;                // exclusive prefix (tile base)
  offsets[p] = oc;
  for (int i = 0; i < nt; ++i) {
    tiles[(ot + i) * 4 + 0] = p;
    tiles[(ot + i) * 4 + 1] = oc + i * BM;
    tiles[(ot + i) * 4 + 2] = (c - i * BM) < BM ? (c - i * BM) : BM;
    tiles[(ot + i) * 4 + 3] = 0;
  }
  if (p == 63) *ntiles = itt;
}

// ---- K3: build permutation (tiny) ----
__global__ __launch_bounds__(256) void perm_build(const int* __restrict__ pairs,
                                                  const int* __restrict__ offsets,
                                                  int* __restrict__ cursors,
                                                  int* __restrict__ perm) {
  int t = blockIdx.x * 256 + threadIdx.x;
  int pr = pairs[t];
  int pos = offsets[pr] + atomicAdd(&cursors[pr], 1);
  perm[pos] = t;
}

// ---- K4: pair-group GEMM.  out[tok,h] = 0.5*(A.(W[e1]+W[e2])^T + b[e1]+b[e2]) ----
// 128x128 tile, BK=64, 4 waves (2x2), 16x16x32 bf16 MFMA, two B panels into one acc.
// A rows gathered in-flight: per-lane global source = xbf[perm[row]] (LDS dest linear).
// XOR swizzle (rule #21): source col pre-swizzled (slot ^= row&7); reads apply same XOR.
__global__ __launch_bounds__(256) void moe_gemm(const unsigned short* __restrict__ xbf,
                                                const unsigned short* __restrict__ Wbf,
                                                const float* __restrict__ bvec,
                                                const int* __restrict__ perm,
                                                const int* __restrict__ tiles,
                                                const int* __restrict__ ntiles_p,
                                                float* __restrict__ out) {
  int bt = blockIdx.x;
  if (bt >= *ntiles_p) return;
  int4 tt = ((const int4*)tiles)[bt];
  int pair = tt.x, row0 = tt.y, nrows = tt.z;
  int e1 = pair >> 3, e2 = pair & 7;
  int col0 = blockIdx.y * BN;

  __shared__ __align__(16) unsigned short As[BM * BK];
  __shared__ __align__(16) unsigned short Bs1[BN * BK];
  __shared__ __align__(16) unsigned short Bs2[BN * BK];

  int w = threadIdx.x >> 6;
  int lane = threadIdx.x & 63;
  int wm = w >> 1, wn = w & 1;

  // staging geometry: round r (0..3) covers rows [r*32, r*32+32)
  // wave w covers rows r*32 + w*8 + (lane>>3); 16B chunk (lane&7) of the 128B row,
  // source-swizzled: chunk_src = (lane&7) ^ (row&7), row&7 == lane>>3
  int srow = w * 8 + (lane >> 3);                 // row within 32-row round
  int scol = (((lane & 7) ^ (lane >> 3)) * 8);    // element offset, pre-swizzled
  int ldsoff = w * 1024 + lane * 16;              // linear bytes within 4KB round

  // gather A source rows through perm (per-lane source addresses are legal)
  const unsigned short* Ags[4];
#pragma unroll
  for (int r = 0; r < 4; ++r) {
    int gr = row0 + r * 32 + srow;
    gr = gr < T_TOK ? gr : T_TOK - 1;   // clamp; excess rows masked at store
    Ags[r] = xbf + (size_t)perm[gr] * D_DIM + scol;
  }
  const unsigned short* B1g0 = Wbf + ((size_t)e1 * H_DIM + col0 + srow) * D_DIM + scol;
  const unsigned short* B2g0 = Wbf + ((size_t)e2 * H_DIM + col0 + srow) * D_DIM + scol;

  int fr = lane & 15;
  int kslot = (lane >> 4) * 16;   // byte offset of this lane's 16B slot in 64B half
  int swz = (fr & 7) << 4;        // read-side XOR key (row&7 == fr&7)

  f32x4 acc[4][4] = {};

  for (int kt = 0; kt < D_DIM / BK; ++kt) {
    int k0 = kt * BK;
#pragma unroll
    for (int r = 0; r < 4; ++r) {
      gld16((char*)As  + r * 4096 + ldsoff, Ags[r] + k0);
      gld16((char*)Bs1 + r * 4096 + ldsoff, B1g0 + (size_t)r * 32 * D_DIM + k0);
      gld16((char*)Bs2 + r * 4096 + ldsoff, B2g0 + (size_t)r * 32 * D_DIM + k0);
    }
    __syncthreads();

#pragma unroll
    for (int ks = 0; ks < 2; ++ks) {
      int cb = (ks * 64 + kslot) ^ swz;   // swizzled byte col within 128B row
      bf16x8 a[4], b1[4], b2[4];
#pragma unroll
      for (int i = 0; i < 4; ++i) {
        a[i]  = *(const bf16x8*)((const char*)As  + (wm * 64 + i * 16 + fr) * 128 + cb);
        b1[i] = *(const bf16x8*)((const char*)Bs1 + (wn * 64 + i * 16 + fr) * 128 + cb);
        b2[i] = *(const bf16x8*)((const char*)Bs2 + (wn * 64 + i * 16 + fr) * 128 + cb);
      }
#pragma unroll
      for (int mi = 0; mi < 4; ++mi)
#pragma unroll
        for (int ni = 0; ni < 4; ++ni) {
          acc[mi][ni] = __builtin_amdgcn_mfma_f32_16x16x32_bf16(a[mi], b1[ni], acc[mi][ni], 0, 0, 0);
          acc[mi][ni] = __builtin_amdgcn_mfma_f32_16x16x32_bf16(a[mi], b2[ni], acc[mi][ni], 0, 0, 0);
        }
    }
    __syncthreads();
  }

  // epilogue: C/D layout col=lane&15, row=(lane>>4)*4+j (verified m89/m91)
  int toks[4][4];
  bool okr[4][4];
#pragma unroll
  for (int mi = 0; mi < 4; ++mi)
#pragma unroll
    for (int j = 0; j < 4; ++j) {
      int rl = wm * 64 + mi * 16 + (lane >> 4) * 4 + j;
      okr[mi][j] = rl < nrows;
      toks[mi][j] = okr[mi][j] ? perm[row0 + rl] : 0;
    }
#pragma unroll
  for (int ni = 0; ni < 4; ++ni) {
    int h = col0 + wn * 64 + ni * 16 + fr;
    float bias = 0.5f * (bvec[e1 * H_DIM + h] + bvec[e2 * H_DIM + h]);
#pragma unroll
    for (int mi = 0; mi < 4; ++mi)
#pragma unroll
      for (int j = 0; j < 4; ++j)
        if (okr[mi][j])
          out[(size_t)toks[mi][j] * H_DIM + h] = 0.5f * acc[mi][ni][j] + bias;
  }
}

extern "C" void kernel_launch(void* const* d_in, const int* in_sizes, int n_in,
                              void* d_out, int out_size, void* d_ws, size_t ws_size,
                              hipStream_t stream) {
  const float* seq = (const float*)d_in[0];   // [4,2048,1024]
  const float* gw  = (const float*)d_in[1];   // [8,1024]
  const float* gb  = (const float*)d_in[2];   // [8]
  const float* W   = (const float*)d_in[3];   // [8,4096,1024]
  const float* bb  = (const float*)d_in[4];   // [8,4096]
  float* out = (float*)d_out;

  char* ws = (char*)d_ws;
  int* counts  = (int*)(ws + OFF_COUNTS);
  int* cursors = (int*)(ws + OFF_CURSORS);
  int* offsets = (int*)(ws + OFF_OFFSETS);
  int* ntiles  = (int*)(ws + OFF_NTILES);
  int* tiles   = (int*)(ws + OFF_TILES);
  int* pairs   = (int*)(ws + OFF_PAIRS);
  int* perm    = (int*)(ws + OFF_PERM);
  unsigned short* xbf = (unsigned short*)(ws + OFF_XBF);
  unsigned short* Wbf = (unsigned short*)(ws + OFF_WBF);

  hipMemsetAsync(d_ws, 0, 1024, stream);

  conv_w<<<dim3((E_EXP * H_DIM * D_DIM) / 8 / 256), dim3(256), 0, stream>>>(W, Wbf);
  gate_topk<<<dim3(T_TOK / 4), dim3(256), 0, stream>>>(seq, gw, gb, pairs, counts, xbf);
  scan_tiles<<<dim3(1), dim3(64), 0, stream>>>(counts, offsets, tiles, ntiles);
  perm_build<<<dim3(T_TOK / 256), dim3(256), 0, stream>>>(pairs, offsets, cursors, perm);
  moe_gemm<<<dim3(MAX_TILES, H_DIM / BN), dim3(256), 0, stream>>>(xbf, Wbf, bb, perm, tiles, ntiles, out);
}